// Round 4
// baseline (148.757 us; speedup 1.0000x reference)
//
#include <hip/hip_runtime.h>

// EnsembleGRU, R4: 3-kernel split to decouple the parallel (memory-heavy)
// gi precompute from the serial (light) scan.
//   fold: M[e] = W_ih[e]·W_lin[e] (3x8) + biases, prescaled by -L2E (gates r,z)
//         and +2*L2E (gate n) -> mc[E][3][12] in ws.
//   gi:   gi[w,g,chain] = M[g]·x[w,chain] + c[g]   (fully parallel, coalesced)
//   scan: h_t = (1-z)n + z h  with r=rcp(1+exp2(.)), n=1-2rcp(1+exp2(.))
// Probe rationale: R0 and R1 (different kernels) both timed 135.8 us +-11ns and
// never appeared in rocprof top-5 (<50us) -> dur includes harness fills; this
// split forces the kernel-time component to move and exposes gi_kernel to PMC.

namespace {
constexpr int W_T = 64;
constexpr int E_N = 16;
constexpr int F_N = 8;
constexpr int PROJ = 16;
constexpr int BI = 2560;                 // B*I
constexpr int OST = E_N * BI;            // 40960 chains
constexpr int TOT = W_T * OST;           // 2,621,440 (w,chain) pairs
constexpr int BLOCKS_PER_W = OST / 256;  // 160
constexpr int BLOCKS_PER_E_SCAN = BI / 64; // 40
constexpr float L2E = 1.44269504088896340736f;
constexpr int MC_STRIDE = 12;            // floats per (e,g) row
constexpr size_t MC_BYTES = 4096;        // mc region size in ws (aligned pad)
} // namespace

// ---------------- fold: 1 block, 48 active threads ----------------
__global__ void gru_fold_kernel(const float* __restrict__ wl,   // (E,16,8)
                                const float* __restrict__ bl,   // (E,16)
                                const float* __restrict__ wih,  // (E,3,16)
                                const float* __restrict__ whh,  // (E,3)
                                const float* __restrict__ bih,  // (E,3)
                                const float* __restrict__ bhh,  // (E,3)
                                float* __restrict__ mc)         // (E,3,12)
{
    const int t = threadIdx.x;
    if (t >= E_N * 3) return;
    const int e = t / 3, g = t % 3;
    const float* wl_e = wl + e * (PROJ * F_N);
    const float* wih_eg = wih + e * (3 * PROJ) + g * PROJ;
    float m[F_N];
    #pragma unroll
    for (int f = 0; f < F_N; ++f) m[f] = 0.f;
    float c = bih[e * 3 + g];
    #pragma unroll
    for (int o = 0; o < PROJ; ++o) {
        const float wgo = wih_eg[o];
        c = __builtin_fmaf(wgo, bl[e * PROJ + o], c);
        #pragma unroll
        for (int f = 0; f < F_N; ++f)
            m[f] = __builtin_fmaf(wgo, wl_e[o * F_N + f], m[f]);
    }
    const float scale = (g == 2) ? (2.f * L2E) : (-L2E);
    float* p = mc + (e * 3 + g) * MC_STRIDE;
    #pragma unroll
    for (int f = 0; f < F_N; ++f) p[f] = scale * m[f];
    p[8] = (g == 2) ? scale * c : scale * (c + bhh[e * 3 + g]);
    p[9] = scale * whh[e * 3 + g];
    p[10] = (g == 2) ? scale * bhh[e * 3 + 2] : 0.f;
    p[11] = 0.f;
}

// ---------------- gi: fully parallel precompute ----------------
__global__ __launch_bounds__(256) void gru_gi_kernel(
    const float* __restrict__ x,   // (W,E,BI,8)
    const float* __restrict__ mc,  // (E,3,12)
    float* __restrict__ gi)        // (W,3,OST)
{
    const int b = blockIdx.x;
    const int w = b / BLOCKS_PER_W;             // block-uniform
    const int e = (b % BLOCKS_PER_W) / 10;      // block-uniform (BI/256==10)
    const int idx = b * 256 + (int)threadIdx.x; // (w,chain) flat
    const int chain = idx - w * OST;

    const float* mcp = mc + e * (3 * MC_STRIDE);  // SGPR-addressed (b-derived)
    const float4 A4 = *(const float4*)(x + (size_t)idx * F_N);
    const float4 B4 = *(const float4*)(x + (size_t)idx * F_N + 4);
    const float xv[8] = {A4.x, A4.y, A4.z, A4.w, B4.x, B4.y, B4.z, B4.w};

    float a0 = mcp[8], a1 = mcp[MC_STRIDE + 8], a2 = mcp[2 * MC_STRIDE + 8];
    #pragma unroll
    for (int f = 0; f < F_N; ++f) {
        a0 = __builtin_fmaf(mcp[f], xv[f], a0);
        a1 = __builtin_fmaf(mcp[MC_STRIDE + f], xv[f], a1);
        a2 = __builtin_fmaf(mcp[2 * MC_STRIDE + f], xv[f], a2);
    }
    gi[(size_t)(w * 3 + 0) * OST + chain] = a0;
    gi[(size_t)(w * 3 + 1) * OST + chain] = a1;
    gi[(size_t)(w * 3 + 2) * OST + chain] = a2;
}

// ---------------- scan: serial over W, light loads ----------------
__global__ __launch_bounds__(64, 1) void gru_scan_kernel(
    const float* __restrict__ gi,   // (W,3,OST)
    const float* __restrict__ h0p,  // (E,BI)
    const float* __restrict__ mc,   // (E,3,12)
    float* __restrict__ out)        // (W,OST)
{
    const int e = blockIdx.x / BLOCKS_PER_E_SCAN;        // block-uniform
    const int chain = blockIdx.x * 64 + (int)threadIdx.x;

    const float* mcp = mc + e * (3 * MC_STRIDE);
    const float W0s = mcp[9];
    const float W1s = mcp[MC_STRIDE + 9];
    const float W2s = mcp[2 * MC_STRIDE + 9];
    const float bh2s = mcp[2 * MC_STRIDE + 10];

    float h = h0p[chain];

    constexpr int CH2 = 16;
    float g0A[CH2], g1A[CH2], g2A[CH2], g0B[CH2], g1B[CH2], g2B[CH2];

    auto LOAD = [&](float (&g0)[CH2], float (&g1)[CH2], float (&g2)[CH2], int c) {
        #pragma unroll
        for (int j = 0; j < CH2; ++j) {
            const int t = c * CH2 + j;
            g0[j] = gi[(size_t)(t * 3 + 0) * OST + chain];
            g1[j] = gi[(size_t)(t * 3 + 1) * OST + chain];
            g2[j] = gi[(size_t)(t * 3 + 2) * OST + chain];
        }
    };
    auto COMP = [&](const float (&g0)[CH2], const float (&g1)[CH2],
                    const float (&g2)[CH2], int c) {
        #pragma unroll
        for (int j = 0; j < CH2; ++j) {
            const float r = __builtin_amdgcn_rcpf(
                1.f + __builtin_amdgcn_exp2f(__builtin_fmaf(W0s, h, g0[j])));
            const float z = __builtin_amdgcn_rcpf(
                1.f + __builtin_amdgcn_exp2f(__builtin_fmaf(W1s, h, g1[j])));
            const float t2 = __builtin_fmaf(r, __builtin_fmaf(W2s, h, bh2s), g2[j]);
            const float n = __builtin_fmaf(
                -2.f, __builtin_amdgcn_rcpf(1.f + __builtin_amdgcn_exp2f(t2)), 1.f);
            h = __builtin_fmaf(z, h - n, n);
            out[(size_t)(c * CH2 + j) * OST + chain] = h;
        }
    };

    LOAD(g0A, g1A, g2A, 0);
    LOAD(g0B, g1B, g2B, 1);
    COMP(g0A, g1A, g2A, 0);
    LOAD(g0A, g1A, g2A, 2);
    COMP(g0B, g1B, g2B, 1);
    LOAD(g0B, g1B, g2B, 3);
    COMP(g0A, g1A, g2A, 2);
    COMP(g0B, g1B, g2B, 3);
}

extern "C" void kernel_launch(void* const* d_in, const int* in_sizes, int n_in,
                              void* d_out, int out_size, void* d_ws, size_t ws_size,
                              hipStream_t stream) {
    const float* x   = (const float*)d_in[0];
    const float* st  = (const float*)d_in[1];
    const float* wl  = (const float*)d_in[2];
    const float* bl  = (const float*)d_in[3];
    const float* wih = (const float*)d_in[4];
    const float* whh = (const float*)d_in[5];
    const float* bih = (const float*)d_in[6];
    const float* bhh = (const float*)d_in[7];
    float* out = (float*)d_out;

    float* mc = (float*)d_ws;                       // 576 floats (4 KB region)
    float* gi = (float*)((char*)d_ws + MC_BYTES);   // W*3*OST floats = 31.5 MB

    hipLaunchKernelGGL(gru_fold_kernel, dim3(1), dim3(64), 0, stream,
                       wl, bl, wih, whh, bih, bhh, mc);
    hipLaunchKernelGGL(gru_gi_kernel, dim3(TOT / 256), dim3(256), 0, stream,
                       x, mc, gi);
    hipLaunchKernelGGL(gru_scan_kernel, dim3(OST / 64), dim3(64), 0, stream,
                       gi, st, mc, out);
}

// Round 5
// 136.253 us; speedup vs baseline: 1.0918x; 1.0918x over previous
//
#include <hip/hip_runtime.h>

// EnsembleGRU fused kernel — R5 = revert to R1 single-kernel (best: 135.8 us).
// R4's 3-kernel split regressed +13 us == exactly its extra 63 MB of gi
// materialization traffic at 6.3 TB/s + 2 extra launches -> marginal kernel
// cost prices at HBM BW; single kernel with compulsory traffic (84 MB read x,
// 10.5 MB write out) is the roofline configuration.
//
// Math fold: gi = W_ih·(W_lin·x + b_lin) + b_ih  ==  M·x + c, M = W_ih·W_lin (3x8).
// Gates pre-scaled so each is rcp(1+exp2(fma)):
//   r = sigmoid(a) = rcp(1 + exp2(-L2E*a))        (fold -L2E into M0,c0,w0)
//   z likewise; n = tanh(t) = 1 - 2*rcp(1+exp2(2*L2E*t)) (fold 2*L2E into M2,...)
// Named double buffers bA/bB: compile-time indices only -> register-resident.

namespace {
constexpr int W_T = 64;
constexpr int E_N = 16;
constexpr int B_N = 256;
constexpr int I_N = 10;
constexpr int F_N = 8;
constexpr int PROJ = 16;
constexpr int BI = B_N * I_N;           // 2560
constexpr int WSTRIDE = E_N * BI * F_N; // 327680 floats per timestep
constexpr int OSTRIDE = E_N * BI;       // 40960 floats per timestep
constexpr int NCHAIN = E_N * BI;        // 40960 chains
constexpr int BLOCKS_PER_E = BI / 64;   // 40
constexpr float L2E = 1.44269504088896340736f;
constexpr int CH = 8;                   // timesteps per chunk
constexpr int NC = W_T / CH;            // 8 chunks
} // namespace

__global__ __launch_bounds__(64, 1) void EnsembleGRUModule_63213328662935_kernel(
    const float* __restrict__ x,    // (W,E,BI,F)
    const float* __restrict__ h0p,  // (1,E,BI,1)
    const float* __restrict__ wl,   // (E,16,8)
    const float* __restrict__ bl,   // (E,16)
    const float* __restrict__ wih,  // (E,3,16)
    const float* __restrict__ whh,  // (E,3,1)
    const float* __restrict__ bih,  // (E,3)
    const float* __restrict__ bhh,  // (E,3)
    float* __restrict__ out)        // (W,E,BI)
{
    const int e = blockIdx.x / BLOCKS_PER_E;            // block-uniform -> scalar loads
    const int bi = (blockIdx.x % BLOCKS_PER_E) * 64 + threadIdx.x;
    const int chain = e * BI + bi;

    // ---- fold the two linear layers: M[3][8], c[3] (one-time, ~400 FMA) ----
    const float* wl_e = wl + e * (PROJ * F_N);
    const float* wih_e = wih + e * (3 * PROJ);
    float M[3][F_N];
    float c[3];
    #pragma unroll
    for (int g = 0; g < 3; ++g) {
        float cg = bih[e * 3 + g];
        float m[F_N];
        #pragma unroll
        for (int f = 0; f < F_N; ++f) m[f] = 0.f;
        #pragma unroll
        for (int o = 0; o < PROJ; ++o) {
            const float wgo = wih_e[g * PROJ + o];
            cg = __builtin_fmaf(wgo, bl[e * PROJ + o], cg);
            #pragma unroll
            for (int f = 0; f < F_N; ++f)
                m[f] = __builtin_fmaf(wgo, wl_e[o * F_N + f], m[f]);
        }
        #pragma unroll
        for (int f = 0; f < F_N; ++f) M[g][f] = m[f];
        c[g] = cg;
    }
    // ---- pre-scale for exp2-form gates ----
    float M0[F_N], M1[F_N], M2[F_N];
    #pragma unroll
    for (int f = 0; f < F_N; ++f) {
        M0[f] = -L2E * M[0][f];
        M1[f] = -L2E * M[1][f];
        M2[f] = 2.f * L2E * M[2][f];
    }
    const float c0s = -L2E * (c[0] + bhh[e * 3 + 0]);
    const float c1s = -L2E * (c[1] + bhh[e * 3 + 1]);
    const float c2s = 2.f * L2E * c[2];
    const float W0s = -L2E * whh[e * 3 + 0];
    const float W1s = -L2E * whh[e * 3 + 1];
    const float W2s = 2.f * L2E * whh[e * 3 + 2];
    const float bh2s = 2.f * L2E * bhh[e * 3 + 2];

    const float* xp = x + (size_t)chain * F_N;
    float* op = out + chain;
    float h = h0p[chain];

    // ---- named double buffers: registers guaranteed (constant indices only) ----
    float4 bA[CH][2], bB[CH][2];

    auto LOADC = [&](float4 (&b)[CH][2], int cidx) {
        #pragma unroll
        for (int j = 0; j < CH; ++j) {
            const float* p = xp + (size_t)(cidx * CH + j) * WSTRIDE;
            b[j][0] = *(const float4*)p;
            b[j][1] = *(const float4*)(p + 4);
        }
    };
    auto COMPUTE = [&](const float4 (&b)[CH][2], int cidx) {
        // hoisted h-independent gate pre-activations for the whole chunk
        float g0[CH], g1[CH], g2[CH];
        #pragma unroll
        for (int j = 0; j < CH; ++j) {
            const float xv[8] = {b[j][0].x, b[j][0].y, b[j][0].z, b[j][0].w,
                                 b[j][1].x, b[j][1].y, b[j][1].z, b[j][1].w};
            float a0 = c0s, a1 = c1s, a2 = c2s;
            #pragma unroll
            for (int f = 0; f < 8; ++f) {
                a0 = __builtin_fmaf(M0[f], xv[f], a0);
                a1 = __builtin_fmaf(M1[f], xv[f], a1);
                a2 = __builtin_fmaf(M2[f], xv[f], a2);
            }
            g0[j] = a0; g1[j] = a1; g2[j] = a2;
        }
        // serial h-chain
        #pragma unroll
        for (int j = 0; j < CH; ++j) {
            const float r  = __builtin_amdgcn_rcpf(
                1.f + __builtin_amdgcn_exp2f(__builtin_fmaf(W0s, h, g0[j])));
            const float z  = __builtin_amdgcn_rcpf(
                1.f + __builtin_amdgcn_exp2f(__builtin_fmaf(W1s, h, g1[j])));
            const float gh2 = __builtin_fmaf(W2s, h, bh2s);
            const float t   = __builtin_fmaf(r, gh2, g2[j]);
            const float n   = __builtin_fmaf(
                -2.f, __builtin_amdgcn_rcpf(1.f + __builtin_amdgcn_exp2f(t)), 1.f);
            h = __builtin_fmaf(z, h - n, n);
            op[(size_t)(cidx * CH + j) * OSTRIDE] = h;
        }
    };

    LOADC(bA, 0);
    LOADC(bB, 1);
    #pragma unroll
    for (int cidx = 0; cidx < NC; cidx += 2) {
        COMPUTE(bA, cidx);
        if (cidx + 2 < NC) LOADC(bA, cidx + 2);   // in flight under COMPUTE(bB)
        COMPUTE(bB, cidx + 1);
        if (cidx + 3 < NC) LOADC(bB, cidx + 3);   // in flight under next COMPUTE(bA)
    }
}

extern "C" void kernel_launch(void* const* d_in, const int* in_sizes, int n_in,
                              void* d_out, int out_size, void* d_ws, size_t ws_size,
                              hipStream_t stream) {
    const float* x   = (const float*)d_in[0];
    const float* st  = (const float*)d_in[1];
    const float* wl  = (const float*)d_in[2];
    const float* bl  = (const float*)d_in[3];
    const float* wih = (const float*)d_in[4];
    const float* whh = (const float*)d_in[5];
    const float* bih = (const float*)d_in[6];
    const float* bhh = (const float*)d_in[7];
    float* out = (float*)d_out;

    dim3 grid(NCHAIN / 64);
    dim3 block(64);
    hipLaunchKernelGGL(EnsembleGRUModule_63213328662935_kernel, grid, block, 0, stream,
                       x, st, wl, bl, wih, whh, bih, bhh, out);
}